// Round 21
// baseline (347.886 us; speedup 1.0000x reference)
//
#include <hip/hip_runtime.h>
#include <hip/hip_bf16.h>
#include <stdint.h>

typedef __bf16 bf16_t;
typedef __bf16 bf16x8 __attribute__((ext_vector_type(8)));
typedef __bf16 bf16x4_t __attribute__((ext_vector_type(4)));
typedef float f32x4 __attribute__((ext_vector_type(4)));
typedef float f32x16 __attribute__((ext_vector_type(16)));
typedef unsigned int u32x4 __attribute__((ext_vector_type(4)));

#define B_   2
#define H_   16
#define D_   64
#define LQ_  2048
#define LC_  2048
#define M_   1024

#define EXP2(x) __builtin_amdgcn_exp2f(x)

__device__ __forceinline__ void gload_lds16(const void* g, void* l) {
  __builtin_amdgcn_global_load_lds((__attribute__((address_space(1))) unsigned int*)(g),
                                   (__attribute__((address_space(3))) unsigned int*)(l),
                                   16, 0, 0);
}

__device__ __forceinline__ unsigned pack2(float a, float b) {
  __bf16 x = (__bf16)a, y = (__bf16)b;
  unsigned short ux = __builtin_bit_cast(unsigned short, x);
  unsigned short uy = __builtin_bit_cast(unsigned short, y);
  return (unsigned)ux | ((unsigned)uy << 16);
}

// ---------------- merged prep: input cvt + 3 weight transposes, one dispatch ----------------
__global__ void prep_kernel(const float* __restrict__ query, const float* __restrict__ context,
                            bf16_t* __restrict__ queryb, bf16_t* __restrict__ ctxb,
                            const float* __restrict__ Wq, const float* __restrict__ Wkv,
                            const float* __restrict__ Wout,
                            bf16_t* __restrict__ Wq_t, bf16_t* __restrict__ Wkv_t,
                            bf16_t* __restrict__ Wout_t) {
  __shared__ float tile[32][33];
  const int bid = blockIdx.x;
  if (bid < 8192) {
    const int n4each = 4096 * 1024 / 4;
    int i = bid * 256 + threadIdx.x;
    const float* in = (i < n4each) ? query : context;
    bf16_t* out = (i < n4each) ? queryb : ctxb;
    const int j = (i < n4each) ? i : (i - n4each);
    const float4 f = ((const float4*)in)[j];
    bf16x4_t o4;
    o4[0] = (__bf16)f.x; o4[1] = (__bf16)f.y; o4[2] = (__bf16)f.z; o4[3] = (__bf16)f.w;
    ((bf16x4_t*)out)[j] = o4;
    return;
  }
  int tb = bid - 8192;
  const float* in; bf16_t* out; int N, kvperm;
  if (tb < 1024)      { in = Wq;   out = Wq_t;   N = 1024; kvperm = 0; }
  else if (tb < 3072) { tb -= 1024; in = Wkv;  out = Wkv_t;  N = 2048; kvperm = 1; }
  else                { tb -= 3072; in = Wout; out = Wout_t; N = 1024; kvperm = 0; }
  const int K = 1024;
  const int nb = N / 32;
  const int n0 = (tb % nb) * 32, k0 = (tb / nb) * 32;
  const int tx = threadIdx.x & 31, ty = threadIdx.x >> 5;
  #pragma unroll
  for (int r = ty; r < 32; r += 8)
    tile[r][tx] = in[(size_t)(k0 + r) * N + (n0 + tx)];
  __syncthreads();
  #pragma unroll
  for (int r = ty; r < 32; r += 8) {
    const int n = n0 + r;
    const int orow = kvperm ? ((n & ~127) | ((n & 1) << 6) | ((n >> 1) & 63)) : n;
    out[(size_t)orow * K + (k0 + tx)] = (__bf16)tile[tx][r];
  }
}

// ---------------- fused Q-proj + KV-proj GEMM v3 (FROZEN): counted-vmcnt dbuf ----------------
__global__ __launch_bounds__(256, 3)
void proj_fused_kernel(const bf16_t* __restrict__ Aq, const bf16_t* __restrict__ Akv,
                       const bf16_t* __restrict__ Wq_t, const bf16_t* __restrict__ Wkv_t,
                       const float* __restrict__ bq, const float* __restrict__ bkv,
                       bf16_t* __restrict__ q_s, bf16_t* __restrict__ k_s,
                       bf16_t* __restrict__ v_t) {
  __shared__ __attribute__((aligned(16))) bf16_t ldsA[2][128 * 64];
  __shared__ __attribute__((aligned(16))) bf16_t ldsB[2][64 * 64];
  const int tid  = threadIdx.x;
  const int wave = tid >> 6, lane = tid & 63;
  const int bid  = blockIdx.x + 48 * blockIdx.y;
  const int nbid = (bid & 7) * 192 + (bid >> 3);
  const int ny = nbid / 48, nx = nbid % 48;
  const bool isq = (nx < 16);
  const bf16_t* A  = isq ? Aq : Akv;
  const bf16_t* Bt = isq ? Wq_t : Wkv_t;
  const int n0 = (isq ? nx : (nx - 16)) * 64;
  const int m0 = ny * 128;
  const int K  = 1024;
  const int wr = wave >> 1, wc = wave & 1;
  const int lrow = lane & 15, lg = lane >> 4;
  const int srow = lane >> 3;
  const int sc8  = ((lane & 7) ^ srow) * 8;

#define PSTAGE(T, BUF) do {                                                      \
    const int kk_ = (T) * 64;                                                    \
    _Pragma("unroll")                                                            \
    for (int i_ = 0; i_ < 4; ++i_) {                                             \
      const int c_ = wave * 4 + i_;                                              \
      gload_lds16(A + (size_t)(m0 + c_ * 8 + srow) * K + (kk_ + sc8),            \
                  ldsA[BUF] + c_ * 512);                                         \
    }                                                                            \
    _Pragma("unroll")                                                            \
    for (int i_ = 0; i_ < 2; ++i_) {                                             \
      const int c_ = wave * 2 + i_;                                              \
      gload_lds16(Bt + (size_t)(n0 + c_ * 8 + srow) * K + (kk_ + sc8),           \
                  ldsB[BUF] + c_ * 512);                                         \
    }                                                                            \
  } while (0)

  f32x4 acc[4][2] = {};

  PSTAGE(0, 0);
  asm volatile("s_waitcnt vmcnt(0)" ::: "memory");
  __builtin_amdgcn_s_barrier();
  PSTAGE(1, 1);

  #pragma unroll 1
  for (int kt = 0; kt < 16; ++kt) {
    const int buf = kt & 1;
    bf16x8 af[2][4], bfv[2][2];
    #pragma unroll
    for (int ks = 0; ks < 2; ++ks) {
      #pragma unroll
      for (int mi = 0; mi < 4; ++mi)
        af[ks][mi] = *(const bf16x8*)(ldsA[buf] + (wr * 64 + mi * 16 + lrow) * 64 +
                                      (((ks * 4 + lg) ^ (lrow & 7)) * 8));
      #pragma unroll
      for (int ni = 0; ni < 2; ++ni)
        bfv[ks][ni] = *(const bf16x8*)(ldsB[buf] + (wc * 32 + ni * 16 + lrow) * 64 +
                                       (((ks * 4 + lg) ^ (lrow & 7)) * 8));
    }
    asm volatile("s_waitcnt lgkmcnt(0)" ::: "memory");
    __builtin_amdgcn_sched_barrier(0);
    __builtin_amdgcn_s_barrier();

    int t2 = kt + 2; if (t2 > 15) t2 = 15;
    PSTAGE(t2, buf);

    #pragma unroll
    for (int ks = 0; ks < 2; ++ks)
      #pragma unroll
      for (int mi = 0; mi < 4; ++mi)
        #pragma unroll
        for (int ni = 0; ni < 2; ++ni)
          acc[mi][ni] = __builtin_amdgcn_mfma_f32_16x16x32_bf16(af[ks][mi], bfv[ks][ni],
                                                                acc[mi][ni], 0, 0, 0);

    asm volatile("s_waitcnt vmcnt(6)" ::: "memory");
    __builtin_amdgcn_sched_barrier(0);
    __builtin_amdgcn_s_barrier();
  }
#undef PSTAGE

  #pragma unroll
  for (int mi = 0; mi < 4; ++mi) {
    const int rbase = m0 + wr * 64 + mi * 16 + lg * 4;
    #pragma unroll
    for (int ni = 0; ni < 2; ++ni) {
      const int col = n0 + wc * 32 + ni * 16 + lrow;
      if (isq) {
        const float bv = bq[col];
        #pragma unroll
        for (int j = 0; j < 4; ++j)
          q_s[(size_t)(rbase + j) * 1024 + col] =
              (__bf16)((acc[mi][ni][j] + bv) * 0.18033688011112042f);
      } else {
        const int hh = col >> 7, cbit = (col >> 6) & 1, d = col & 63;
        const float bv = bkv[hh * 128 + d * 2 + cbit];
        #pragma unroll
        for (int j = 0; j < 4; ++j) {
          const int row = rbase + j;
          const int bi = row >> 11, lc = row & 2047;
          const float val = acc[mi][ni][j] + bv;
          if (cbit == 0)
            k_s[((size_t)(bi * 16 + hh) * 2048 + lc) * 64 + d] = (__bf16)val;
          else
            v_t[(((size_t)(bi * 16 + hh) * 64 + (lc >> 5)) * 64 + d) * 32 + (lc & 31)] = (__bf16)val;
        }
      }
    }
  }
}

// ---------------- out-proj GEMM v3 (FROZEN): counted-vmcnt dbuf ----------------
__global__ __launch_bounds__(256, 3)
void gemm_out_kernel(const bf16_t* __restrict__ A, const bf16_t* __restrict__ Bt,
                     const float* __restrict__ bias, float* __restrict__ out0) {
  __shared__ __attribute__((aligned(16))) bf16_t ldsA[2][128 * 64];
  __shared__ __attribute__((aligned(16))) bf16_t ldsB[2][64 * 64];
  const int tid  = threadIdx.x;
  const int wave = tid >> 6, lane = tid & 63;
  const int bid  = blockIdx.x + 16 * blockIdx.y;
  const int nbid = (bid & 7) * 64 + (bid >> 3);
  const int m0 = (nbid >> 4) * 128, n0 = (nbid & 15) * 64;
  const int K = 1024, N = 1024;
  const int wr = wave >> 1, wc = wave & 1;
  const int lrow = lane & 15, lg = lane >> 4;
  const int srow = lane >> 3;
  const int sc8  = ((lane & 7) ^ srow) * 8;

#define OSTAGE(T, BUF) do {                                                      \
    const int kk_ = (T) * 64;                                                    \
    _Pragma("unroll")                                                            \
    for (int i_ = 0; i_ < 4; ++i_) {                                             \
      const int c_ = wave * 4 + i_;                                              \
      gload_lds16(A + (size_t)(m0 + c_ * 8 + srow) * K + (kk_ + sc8),            \
                  ldsA[BUF] + c_ * 512);                                         \
    }                                                                            \
    _Pragma("unroll")                                                            \
    for (int i_ = 0; i_ < 2; ++i_) {                                             \
      const int c_ = wave * 2 + i_;                                              \
      gload_lds16(Bt + (size_t)(n0 + c_ * 8 + srow) * K + (kk_ + sc8),           \
                  ldsB[BUF] + c_ * 512);                                         \
    }                                                                            \
  } while (0)

  f32x4 acc[4][2] = {};

  OSTAGE(0, 0);
  asm volatile("s_waitcnt vmcnt(0)" ::: "memory");
  __builtin_amdgcn_s_barrier();
  OSTAGE(1, 1);

  #pragma unroll 1
  for (int kt = 0; kt < 16; ++kt) {
    const int buf = kt & 1;
    bf16x8 af[2][4], bfv[2][2];
    #pragma unroll
    for (int ks = 0; ks < 2; ++ks) {
      #pragma unroll
      for (int mi = 0; mi < 4; ++mi)
        af[ks][mi] = *(const bf16x8*)(ldsA[buf] + (wr * 64 + mi * 16 + lrow) * 64 +
                                      (((ks * 4 + lg) ^ (lrow & 7)) * 8));
      #pragma unroll
      for (int ni = 0; ni < 2; ++ni)
        bfv[ks][ni] = *(const bf16x8*)(ldsB[buf] + (wc * 32 + ni * 16 + lrow) * 64 +
                                       (((ks * 4 + lg) ^ (lrow & 7)) * 8));
    }
    asm volatile("s_waitcnt lgkmcnt(0)" ::: "memory");
    __builtin_amdgcn_sched_barrier(0);
    __builtin_amdgcn_s_barrier();

    int t2 = kt + 2; if (t2 > 15) t2 = 15;
    OSTAGE(t2, buf);

    #pragma unroll
    for (int ks = 0; ks < 2; ++ks)
      #pragma unroll
      for (int mi = 0; mi < 4; ++mi)
        #pragma unroll
        for (int ni = 0; ni < 2; ++ni)
          acc[mi][ni] = __builtin_amdgcn_mfma_f32_16x16x32_bf16(af[ks][mi], bfv[ks][ni],
                                                                acc[mi][ni], 0, 0, 0);

    asm volatile("s_waitcnt vmcnt(6)" ::: "memory");
    __builtin_amdgcn_sched_barrier(0);
    __builtin_amdgcn_s_barrier();
  }
#undef OSTAGE

  #pragma unroll
  for (int mi = 0; mi < 4; ++mi) {
    const int rbase = m0 + wr * 64 + mi * 16 + lg * 4;
    #pragma unroll
    for (int ni = 0; ni < 2; ++ni) {
      const int col = n0 + wc * 32 + ni * 16 + lrow;
      const float bv = bias[col];
      #pragma unroll
      for (int j = 0; j < 4; ++j)
        out0[(size_t)(rbase + j) * N + col] = acc[mi][ni][j] + bv;
    }
  }
}

// ---------------- flash attention v19: v18 + stage/Osh LDS aliasing ----------------
// stage (main loop) and Osh (epilogue) are never live simultaneously -> union
// them: LDS 33.8 -> 17 KB, lifting the blocks/CU cap from 4 to VGPR-bound ~5.
// Safety: the final clamped restage's global_load_lds writes are still in
// flight at loop exit -> one-time vmcnt(0) before the epilogue barrier (each
// wave drains its own queue; the barrier orders cross-wave Osh writes).
// Pin (256,4): cap 128 vs 100 measured VGPR -> 28-reg margin, no spill risk.
// Canary absmax must stay exactly 0.001953125.
__global__ __launch_bounds__(256, 4)
void attn_kernel(const bf16_t* __restrict__ q, const bf16_t* __restrict__ k,
                 const bf16_t* __restrict__ vt, bf16_t* __restrict__ o) {
  __shared__ __attribute__((aligned(16))) unsigned char smem[16384]; // stage[4][2048]bf16 | Osh[64][64]f32
  __shared__ float Lsh[4][2][32];

  bf16_t* stagep = (bf16_t*)smem;
  float*  OshP   = (float*)smem;

  const int tid  = threadIdx.x;
  const int wave = tid >> 6, lane = tid & 63;
  const int li = lane & 31, hi = lane >> 5;

  const int bid  = blockIdx.x;
  const int xcd  = bid & 7, slot = bid >> 3;
  const int bh   = xcd * 4 + (slot >> 5);
  const int qt   = slot & 31;
  const int b    = bh >> 4, h = bh & 15;

  bf16x8 qa[2][4];
  #pragma unroll
  for (int g = 0; g < 2; ++g) {
    const bf16_t* qp = q + (size_t)(b * LQ_ + qt * 64 + g * 32 + li) * 1024 + h * 64 + hi * 8;
    #pragma unroll
    for (int ks = 0; ks < 4; ++ks) qa[g][ks] = *(const bf16x8*)(qp + ks * 16);
  }
  asm volatile("s_waitcnt vmcnt(0)" ::: "memory");

  const int kv0 = wave * (LC_ / 4);
  const bf16_t* kbase  = k  + (size_t)bh * LC_ * 64 + (size_t)kv0 * 64;
  const bf16_t* vtbase = vt + ((size_t)bh * 64 + wave * 16) * 2048;

  const size_t koff = (size_t)(lane >> 3) * 64 + (size_t)(((lane & 7) ^ (lane >> 3)) * 8);

  bf16_t* lk = stagep + wave * 2048;

#define STAGE_K(T) do {                                                          \
    const bf16_t* kc_ = kbase + (size_t)(T) * 2048;                              \
    _Pragma("unroll")                                                            \
    for (int i_ = 0; i_ < 4; ++i_)                                               \
      gload_lds16(kc_ + koff + (size_t)i_ * 512, lk + i_ * 512);                 \
  } while (0)

  f32x16 oaccA[2] = {};
  f32x16 oaccB[2] = {};
  float l_run0 = 0.f, l_run1 = 0.f;

  STAGE_K(0);

  #pragma unroll 1
  for (int t = 0; t < 16; ++t) {
    asm volatile("s_waitcnt vmcnt(0)" ::: "memory");
    __builtin_amdgcn_sched_barrier(0);

    bf16x8 vf[2][2];
    {
      const bf16_t* vtile = vtbase + (size_t)t * 2048;
      #pragma unroll
      for (int dt = 0; dt < 2; ++dt)
        #pragma unroll
        for (int ks2 = 0; ks2 < 2; ++ks2)
          vf[dt][ks2] = *(const bf16x8*)(vtile + (dt * 32 + li) * 32 + ks2 * 16 + hi * 8);
    }
    __builtin_amdgcn_sched_barrier(0);

    bf16x8 kf[4];
    #pragma unroll
    for (int ks = 0; ks < 4; ++ks)
      kf[ks] = *(const bf16x8*)(lk + li * 64 + (((hi + ks * 2) ^ (li & 7)) * 8));

    asm volatile("s_waitcnt lgkmcnt(0)" ::: "memory");
    __builtin_amdgcn_sched_barrier(0);

    int t2 = t + 1; if (t2 > 15) t2 = 15;
    STAGE_K(t2);

    #pragma unroll
    for (int g = 0; g < 2; ++g) {
      f32x16 sacc = {};
      __builtin_amdgcn_s_setprio(1);
      #pragma unroll
      for (int ks = 0; ks < 4; ++ks)
        sacc = __builtin_amdgcn_mfma_f32_32x32x16_bf16(kf[ks], qa[g][ks], sacc, 0, 0, 0);
      __builtin_amdgcn_s_setprio(0);

      float pv[16]; float ps = 0.f;
      #pragma unroll
      for (int r = 0; r < 16; ++r) { pv[r] = EXP2(sacc[r]); ps += pv[r]; }
      ps += __shfl_xor(ps, 32, 64);
      if (g == 0) l_run0 += ps; else l_run1 += ps;

      unsigned pk[8];
      #pragma unroll
      for (int i = 0; i < 8; ++i) pk[i] = pack2(pv[2 * i], pv[2 * i + 1]);

      unsigned w[8];
      #pragma unroll
      for (int g2 = 0; g2 < 2; ++g2) {
        const int bx = g2 * 4;
        #pragma unroll
        for (int ii = 0; ii < 2; ++ii) {
          const unsigned lo = pk[bx + ii], hi2 = pk[bx + 2 + ii];
          const unsigned s  = hi ? lo : hi2;
          const unsigned xs = __shfl_xor(s, 32, 64);
          w[bx + ii]     = hi ? xs  : lo;
          w[bx + 2 + ii] = hi ? hi2 : xs;
        }
      }
      const u32x4 pw0 = {w[0], w[1], w[2], w[3]};
      const u32x4 pw1 = {w[4], w[5], w[6], w[7]};
      const bf16x8 pb0 = __builtin_bit_cast(bf16x8, pw0);
      const bf16x8 pb1 = __builtin_bit_cast(bf16x8, pw1);

      __builtin_amdgcn_s_setprio(1);
      if (g == 0) {
        #pragma unroll
        for (int dt = 0; dt < 2; ++dt) {
          oaccA[dt] = __builtin_amdgcn_mfma_f32_32x32x16_bf16(vf[dt][0], pb0, oaccA[dt], 0, 0, 0);
          oaccA[dt] = __builtin_amdgcn_mfma_f32_32x32x16_bf16(vf[dt][1], pb1, oaccA[dt], 0, 0, 0);
        }
      } else {
        #pragma unroll
        for (int dt = 0; dt < 2; ++dt) {
          oaccB[dt] = __builtin_amdgcn_mfma_f32_32x32x16_bf16(vf[dt][0], pb0, oaccB[dt], 0, 0, 0);
          oaccB[dt] = __builtin_amdgcn_mfma_f32_32x32x16_bf16(vf[dt][1], pb1, oaccB[dt], 0, 0, 0);
        }
      }
      __builtin_amdgcn_s_setprio(0);
    }
  }
#undef STAGE_K

  // drain in-flight restage writes before reusing the aliased LDS as Osh
  asm volatile("s_waitcnt vmcnt(0)" ::: "memory");
  if (hi == 0) { Lsh[wave][0][li] = l_run0; Lsh[wave][1][li] = l_run1; }
  __syncthreads();

  #pragma unroll
  for (int ss = 0; ss < 4; ++ss) {
    if (wave == ss) {
      #pragma unroll
      for (int g = 0; g < 2; ++g)
        #pragma unroll
        for (int dt = 0; dt < 2; ++dt)
          #pragma unroll
          for (int r = 0; r < 16; ++r) {
            const int d = dt * 32 + (r & 3) + 8 * (r >> 2) + 4 * hi;
            const float val = (g == 0) ? oaccA[dt][r] : oaccB[dt][r];
            if (ss == 0) OshP[d * 64 + g * 32 + li] = val;
            else         OshP[d * 64 + g * 32 + li] += val;
          }
    }
    __syncthreads();
  }

  // final: normalize + coalesced store (64 q rows)
  #pragma unroll
  for (int rr = 0; rr < 2; ++rr) {
    const int qq = tid >> 3, c8 = (tid & 7) * 8;
    const float lg = Lsh[0][rr][qq] + Lsh[1][rr][qq] + Lsh[2][rr][qq] + Lsh[3][rr][qq];
    const float rl = 1.f / lg;
    u32x4 ow;
    #pragma unroll
    for (int j = 0; j < 4; ++j)
      ow[j] = pack2(OshP[(c8 + 2 * j) * 64 + rr * 32 + qq] * rl,
                    OshP[(c8 + 2 * j + 1) * 64 + rr * 32 + qq] * rl);
    *(u32x4*)(o + (size_t)(b * LQ_ + qt * 64 + rr * 32 + qq) * 1024 + h * 64 + c8) = ow;
  }
}

extern "C" void kernel_launch(void* const* d_in, const int* in_sizes, int n_in,
                              void* d_out, int out_size, void* d_ws, size_t ws_size,
                              hipStream_t stream) {
  const float* query   = (const float*)d_in[0];
  const float* context = (const float*)d_in[1];
  const float* Wq      = (const float*)d_in[2];
  const float* bq      = (const float*)d_in[3];
  const float* Wkv     = (const float*)d_in[4];
  const float* bkv     = (const float*)d_in[5];
  const float* Wout    = (const float*)d_in[6];
  const float* bout    = (const float*)d_in[7];

  char* p = (char*)d_ws;
  bf16_t* queryb = (bf16_t*)p; p += (size_t)4096 * 1024 * 2;
  bf16_t* ctxb   = (bf16_t*)p; p += (size_t)4096 * 1024 * 2;
  bf16_t* Wq_t   = (bf16_t*)p; p += (size_t)1024 * 1024 * 2;
  bf16_t* Wkv_t  = (bf16_t*)p; p += (size_t)2048 * 1024 * 2;
  bf16_t* Wout_t = (bf16_t*)p; p += (size_t)1024 * 1024 * 2;
  bf16_t* q_s    = (bf16_t*)p; p += (size_t)4096 * 1024 * 2;
  bf16_t* k_s    = (bf16_t*)p; p += (size_t)4096 * 1024 * 2;
  bf16_t* v_t    = (bf16_t*)p; p += (size_t)4096 * 1024 * 2;
  bf16_t* attnb  = (bf16_t*)p; p += (size_t)4096 * 1024 * 2;
  if ((size_t)(p - (char*)d_ws) > ws_size) return;

  prep_kernel<<<12288, 256, 0, stream>>>(query, context, queryb, ctxb,
                                         Wq, Wkv, Wout, Wq_t, Wkv_t, Wout_t);
  proj_fused_kernel<<<dim3(48, 32), 256, 0, stream>>>(queryb, ctxb, Wq_t, Wkv_t,
                                                      bq, bkv, q_s, k_s, v_t);
  attn_kernel<<<dim3(1024), 256, 0, stream>>>(q_s, k_s, v_t, attnb);
  gemm_out_kernel<<<dim3(16, 32), 256, 0, stream>>>(attnb, Wout_t, bout, (float*)d_out);
}

// Round 22
// 144.381 us; speedup vs baseline: 2.4095x; 2.4095x over previous
//
#include <hip/hip_runtime.h>
#include <hip/hip_bf16.h>
#include <stdint.h>

typedef __bf16 bf16_t;
typedef __bf16 bf16x8 __attribute__((ext_vector_type(8)));
typedef __bf16 bf16x4_t __attribute__((ext_vector_type(4)));
typedef float f32x4 __attribute__((ext_vector_type(4)));
typedef float f32x16 __attribute__((ext_vector_type(16)));
typedef unsigned int u32x4 __attribute__((ext_vector_type(4)));

#define B_   2
#define H_   16
#define D_   64
#define LQ_  2048
#define LC_  2048
#define M_   1024

#define EXP2(x) __builtin_amdgcn_exp2f(x)

// VGPR-pin rule (learned rounds 16/19/21): __launch_bounds__(256,n) caps the
// allocator at ~256/n VGPRs on gfx950. attn body needs ~100 -> only n=2 is
// spill-free. Never pin above 256/measured-VGPR.

__device__ __forceinline__ void gload_lds16(const void* g, void* l) {
  __builtin_amdgcn_global_load_lds((__attribute__((address_space(1))) unsigned int*)(g),
                                   (__attribute__((address_space(3))) unsigned int*)(l),
                                   16, 0, 0);
}

__device__ __forceinline__ unsigned pack2(float a, float b) {
  __bf16 x = (__bf16)a, y = (__bf16)b;
  unsigned short ux = __builtin_bit_cast(unsigned short, x);
  unsigned short uy = __builtin_bit_cast(unsigned short, y);
  return (unsigned)ux | ((unsigned)uy << 16);
}

// ---------------- merged prep: input cvt + 3 weight transposes, one dispatch ----------------
__global__ void prep_kernel(const float* __restrict__ query, const float* __restrict__ context,
                            bf16_t* __restrict__ queryb, bf16_t* __restrict__ ctxb,
                            const float* __restrict__ Wq, const float* __restrict__ Wkv,
                            const float* __restrict__ Wout,
                            bf16_t* __restrict__ Wq_t, bf16_t* __restrict__ Wkv_t,
                            bf16_t* __restrict__ Wout_t) {
  __shared__ float tile[32][33];
  const int bid = blockIdx.x;
  if (bid < 8192) {
    const int n4each = 4096 * 1024 / 4;
    int i = bid * 256 + threadIdx.x;
    const float* in = (i < n4each) ? query : context;
    bf16_t* out = (i < n4each) ? queryb : ctxb;
    const int j = (i < n4each) ? i : (i - n4each);
    const float4 f = ((const float4*)in)[j];
    bf16x4_t o4;
    o4[0] = (__bf16)f.x; o4[1] = (__bf16)f.y; o4[2] = (__bf16)f.z; o4[3] = (__bf16)f.w;
    ((bf16x4_t*)out)[j] = o4;
    return;
  }
  int tb = bid - 8192;
  const float* in; bf16_t* out; int N, kvperm;
  if (tb < 1024)      { in = Wq;   out = Wq_t;   N = 1024; kvperm = 0; }
  else if (tb < 3072) { tb -= 1024; in = Wkv;  out = Wkv_t;  N = 2048; kvperm = 1; }
  else                { tb -= 3072; in = Wout; out = Wout_t; N = 1024; kvperm = 0; }
  const int K = 1024;
  const int nb = N / 32;
  const int n0 = (tb % nb) * 32, k0 = (tb / nb) * 32;
  const int tx = threadIdx.x & 31, ty = threadIdx.x >> 5;
  #pragma unroll
  for (int r = ty; r < 32; r += 8)
    tile[r][tx] = in[(size_t)(k0 + r) * N + (n0 + tx)];
  __syncthreads();
  #pragma unroll
  for (int r = ty; r < 32; r += 8) {
    const int n = n0 + r;
    const int orow = kvperm ? ((n & ~127) | ((n & 1) << 6) | ((n >> 1) & 63)) : n;
    out[(size_t)orow * K + (k0 + tx)] = (__bf16)tile[tx][r];
  }
}

// ---------------- fused Q-proj + KV-proj GEMM v3 (FROZEN): counted-vmcnt dbuf ----------------
__global__ __launch_bounds__(256, 3)
void proj_fused_kernel(const bf16_t* __restrict__ Aq, const bf16_t* __restrict__ Akv,
                       const bf16_t* __restrict__ Wq_t, const bf16_t* __restrict__ Wkv_t,
                       const float* __restrict__ bq, const float* __restrict__ bkv,
                       bf16_t* __restrict__ q_s, bf16_t* __restrict__ k_s,
                       bf16_t* __restrict__ v_t) {
  __shared__ __attribute__((aligned(16))) bf16_t ldsA[2][128 * 64];
  __shared__ __attribute__((aligned(16))) bf16_t ldsB[2][64 * 64];
  const int tid  = threadIdx.x;
  const int wave = tid >> 6, lane = tid & 63;
  const int bid  = blockIdx.x + 48 * blockIdx.y;
  const int nbid = (bid & 7) * 192 + (bid >> 3);
  const int ny = nbid / 48, nx = nbid % 48;
  const bool isq = (nx < 16);
  const bf16_t* A  = isq ? Aq : Akv;
  const bf16_t* Bt = isq ? Wq_t : Wkv_t;
  const int n0 = (isq ? nx : (nx - 16)) * 64;
  const int m0 = ny * 128;
  const int K  = 1024;
  const int wr = wave >> 1, wc = wave & 1;
  const int lrow = lane & 15, lg = lane >> 4;
  const int srow = lane >> 3;
  const int sc8  = ((lane & 7) ^ srow) * 8;

#define PSTAGE(T, BUF) do {                                                      \
    const int kk_ = (T) * 64;                                                    \
    _Pragma("unroll")                                                            \
    for (int i_ = 0; i_ < 4; ++i_) {                                             \
      const int c_ = wave * 4 + i_;                                              \
      gload_lds16(A + (size_t)(m0 + c_ * 8 + srow) * K + (kk_ + sc8),            \
                  ldsA[BUF] + c_ * 512);                                         \
    }                                                                            \
    _Pragma("unroll")                                                            \
    for (int i_ = 0; i_ < 2; ++i_) {                                             \
      const int c_ = wave * 2 + i_;                                              \
      gload_lds16(Bt + (size_t)(n0 + c_ * 8 + srow) * K + (kk_ + sc8),           \
                  ldsB[BUF] + c_ * 512);                                         \
    }                                                                            \
  } while (0)

  f32x4 acc[4][2] = {};

  PSTAGE(0, 0);
  asm volatile("s_waitcnt vmcnt(0)" ::: "memory");
  __builtin_amdgcn_s_barrier();
  PSTAGE(1, 1);

  #pragma unroll 1
  for (int kt = 0; kt < 16; ++kt) {
    const int buf = kt & 1;
    bf16x8 af[2][4], bfv[2][2];
    #pragma unroll
    for (int ks = 0; ks < 2; ++ks) {
      #pragma unroll
      for (int mi = 0; mi < 4; ++mi)
        af[ks][mi] = *(const bf16x8*)(ldsA[buf] + (wr * 64 + mi * 16 + lrow) * 64 +
                                      (((ks * 4 + lg) ^ (lrow & 7)) * 8));
      #pragma unroll
      for (int ni = 0; ni < 2; ++ni)
        bfv[ks][ni] = *(const bf16x8*)(ldsB[buf] + (wc * 32 + ni * 16 + lrow) * 64 +
                                       (((ks * 4 + lg) ^ (lrow & 7)) * 8));
    }
    asm volatile("s_waitcnt lgkmcnt(0)" ::: "memory");
    __builtin_amdgcn_sched_barrier(0);
    __builtin_amdgcn_s_barrier();

    int t2 = kt + 2; if (t2 > 15) t2 = 15;
    PSTAGE(t2, buf);

    #pragma unroll
    for (int ks = 0; ks < 2; ++ks)
      #pragma unroll
      for (int mi = 0; mi < 4; ++mi)
        #pragma unroll
        for (int ni = 0; ni < 2; ++ni)
          acc[mi][ni] = __builtin_amdgcn_mfma_f32_16x16x32_bf16(af[ks][mi], bfv[ks][ni],
                                                                acc[mi][ni], 0, 0, 0);

    asm volatile("s_waitcnt vmcnt(6)" ::: "memory");
    __builtin_amdgcn_sched_barrier(0);
    __builtin_amdgcn_s_barrier();
  }
#undef PSTAGE

  #pragma unroll
  for (int mi = 0; mi < 4; ++mi) {
    const int rbase = m0 + wr * 64 + mi * 16 + lg * 4;
    #pragma unroll
    for (int ni = 0; ni < 2; ++ni) {
      const int col = n0 + wc * 32 + ni * 16 + lrow;
      if (isq) {
        const float bv = bq[col];
        #pragma unroll
        for (int j = 0; j < 4; ++j)
          q_s[(size_t)(rbase + j) * 1024 + col] =
              (__bf16)((acc[mi][ni][j] + bv) * 0.18033688011112042f);
      } else {
        const int hh = col >> 7, cbit = (col >> 6) & 1, d = col & 63;
        const float bv = bkv[hh * 128 + d * 2 + cbit];
        #pragma unroll
        for (int j = 0; j < 4; ++j) {
          const int row = rbase + j;
          const int bi = row >> 11, lc = row & 2047;
          const float val = acc[mi][ni][j] + bv;
          if (cbit == 0)
            k_s[((size_t)(bi * 16 + hh) * 2048 + lc) * 64 + d] = (__bf16)val;
          else
            v_t[(((size_t)(bi * 16 + hh) * 64 + (lc >> 5)) * 64 + d) * 32 + (lc & 31)] = (__bf16)val;
        }
      }
    }
  }
}

// ---------------- out-proj GEMM v3 (FROZEN): counted-vmcnt dbuf ----------------
__global__ __launch_bounds__(256, 3)
void gemm_out_kernel(const bf16_t* __restrict__ A, const bf16_t* __restrict__ Bt,
                     const float* __restrict__ bias, float* __restrict__ out0) {
  __shared__ __attribute__((aligned(16))) bf16_t ldsA[2][128 * 64];
  __shared__ __attribute__((aligned(16))) bf16_t ldsB[2][64 * 64];
  const int tid  = threadIdx.x;
  const int wave = tid >> 6, lane = tid & 63;
  const int bid  = blockIdx.x + 16 * blockIdx.y;
  const int nbid = (bid & 7) * 64 + (bid >> 3);
  const int m0 = (nbid >> 4) * 128, n0 = (nbid & 15) * 64;
  const int K = 1024, N = 1024;
  const int wr = wave >> 1, wc = wave & 1;
  const int lrow = lane & 15, lg = lane >> 4;
  const int srow = lane >> 3;
  const int sc8  = ((lane & 7) ^ srow) * 8;

#define OSTAGE(T, BUF) do {                                                      \
    const int kk_ = (T) * 64;                                                    \
    _Pragma("unroll")                                                            \
    for (int i_ = 0; i_ < 4; ++i_) {                                             \
      const int c_ = wave * 4 + i_;                                              \
      gload_lds16(A + (size_t)(m0 + c_ * 8 + srow) * K + (kk_ + sc8),            \
                  ldsA[BUF] + c_ * 512);                                         \
    }                                                                            \
    _Pragma("unroll")                                                            \
    for (int i_ = 0; i_ < 2; ++i_) {                                             \
      const int c_ = wave * 2 + i_;                                              \
      gload_lds16(Bt + (size_t)(n0 + c_ * 8 + srow) * K + (kk_ + sc8),           \
                  ldsB[BUF] + c_ * 512);                                         \
    }                                                                            \
  } while (0)

  f32x4 acc[4][2] = {};

  OSTAGE(0, 0);
  asm volatile("s_waitcnt vmcnt(0)" ::: "memory");
  __builtin_amdgcn_s_barrier();
  OSTAGE(1, 1);

  #pragma unroll 1
  for (int kt = 0; kt < 16; ++kt) {
    const int buf = kt & 1;
    bf16x8 af[2][4], bfv[2][2];
    #pragma unroll
    for (int ks = 0; ks < 2; ++ks) {
      #pragma unroll
      for (int mi = 0; mi < 4; ++mi)
        af[ks][mi] = *(const bf16x8*)(ldsA[buf] + (wr * 64 + mi * 16 + lrow) * 64 +
                                      (((ks * 4 + lg) ^ (lrow & 7)) * 8));
      #pragma unroll
      for (int ni = 0; ni < 2; ++ni)
        bfv[ks][ni] = *(const bf16x8*)(ldsB[buf] + (wc * 32 + ni * 16 + lrow) * 64 +
                                       (((ks * 4 + lg) ^ (lrow & 7)) * 8));
    }
    asm volatile("s_waitcnt lgkmcnt(0)" ::: "memory");
    __builtin_amdgcn_sched_barrier(0);
    __builtin_amdgcn_s_barrier();

    int t2 = kt + 2; if (t2 > 15) t2 = 15;
    OSTAGE(t2, buf);

    #pragma unroll
    for (int ks = 0; ks < 2; ++ks)
      #pragma unroll
      for (int mi = 0; mi < 4; ++mi)
        #pragma unroll
        for (int ni = 0; ni < 2; ++ni)
          acc[mi][ni] = __builtin_amdgcn_mfma_f32_16x16x32_bf16(af[ks][mi], bfv[ks][ni],
                                                                acc[mi][ni], 0, 0, 0);

    asm volatile("s_waitcnt vmcnt(6)" ::: "memory");
    __builtin_amdgcn_sched_barrier(0);
    __builtin_amdgcn_s_barrier();
  }
#undef OSTAGE

  #pragma unroll
  for (int mi = 0; mi < 4; ++mi) {
    const int rbase = m0 + wr * 64 + mi * 16 + lg * 4;
    #pragma unroll
    for (int ni = 0; ni < 2; ++ni) {
      const int col = n0 + wc * 32 + ni * 16 + lrow;
      const float bv = bias[col];
      #pragma unroll
      for (int j = 0; j < 4; ++j)
        out0[(size_t)(rbase + j) * N + col] = acc[mi][ni][j] + bv;
    }
  }
}

// ---------------- flash attention v18 (round-20 optimum, FROZEN) ----------------
// 2 q-tiles per wave at (256,2): VGPR 100, no spill, 61.7us measured.
__global__ __launch_bounds__(256, 2)
void attn_kernel(const bf16_t* __restrict__ q, const bf16_t* __restrict__ k,
                 const bf16_t* __restrict__ vt, bf16_t* __restrict__ o) {
  __shared__ __attribute__((aligned(16))) bf16_t stage[4][2048];
  __shared__ float Osh[64][64];          // [d][q] f32 (64 q rows)
  __shared__ float Lsh[4][2][32];

  const int tid  = threadIdx.x;
  const int wave = tid >> 6, lane = tid & 63;
  const int li = lane & 31, hi = lane >> 5;

  // XCD-clustered decode: 8 XCDs x (4 heads x 32 q-tiles-of-64), bijective
  const int bid  = blockIdx.x;
  const int xcd  = bid & 7, slot = bid >> 3;
  const int bh   = xcd * 4 + (slot >> 5);
  const int qt   = slot & 31;
  const int b    = bh >> 4, h = bh & 15;

  bf16x8 qa[2][4];
  #pragma unroll
  for (int g = 0; g < 2; ++g) {
    const bf16_t* qp = q + (size_t)(b * LQ_ + qt * 64 + g * 32 + li) * 1024 + h * 64 + hi * 8;
    #pragma unroll
    for (int ks = 0; ks < 4; ++ks) qa[g][ks] = *(const bf16x8*)(qp + ks * 16);
  }
  asm volatile("s_waitcnt vmcnt(0)" ::: "memory");

  const int kv0 = wave * (LC_ / 4);
  const bf16_t* kbase  = k  + (size_t)bh * LC_ * 64 + (size_t)kv0 * 64;
  const bf16_t* vtbase = vt + ((size_t)bh * 64 + wave * 16) * 2048;

  const size_t koff = (size_t)(lane >> 3) * 64 + (size_t)(((lane & 7) ^ (lane >> 3)) * 8);

  bf16_t* lk = &stage[wave][0];

#define STAGE_K(T) do {                                                          \
    const bf16_t* kc_ = kbase + (size_t)(T) * 2048;                              \
    _Pragma("unroll")                                                            \
    for (int i_ = 0; i_ < 4; ++i_)                                               \
      gload_lds16(kc_ + koff + (size_t)i_ * 512, lk + i_ * 512);                 \
  } while (0)

  f32x16 oaccA[2] = {};
  f32x16 oaccB[2] = {};
  float l_run0 = 0.f, l_run1 = 0.f;

  STAGE_K(0);

  #pragma unroll 1
  for (int t = 0; t < 16; ++t) {
    asm volatile("s_waitcnt vmcnt(0)" ::: "memory");
    __builtin_amdgcn_sched_barrier(0);

    bf16x8 vf[2][2];
    {
      const bf16_t* vtile = vtbase + (size_t)t * 2048;
      #pragma unroll
      for (int dt = 0; dt < 2; ++dt)
        #pragma unroll
        for (int ks2 = 0; ks2 < 2; ++ks2)
          vf[dt][ks2] = *(const bf16x8*)(vtile + (dt * 32 + li) * 32 + ks2 * 16 + hi * 8);
    }
    __builtin_amdgcn_sched_barrier(0);

    bf16x8 kf[4];
    #pragma unroll
    for (int ks = 0; ks < 4; ++ks)
      kf[ks] = *(const bf16x8*)(lk + li * 64 + (((hi + ks * 2) ^ (li & 7)) * 8));

    asm volatile("s_waitcnt lgkmcnt(0)" ::: "memory");
    __builtin_amdgcn_sched_barrier(0);

    int t2 = t + 1; if (t2 > 15) t2 = 15;
    STAGE_K(t2);

    #pragma unroll
    for (int g = 0; g < 2; ++g) {
      f32x16 sacc = {};
      __builtin_amdgcn_s_setprio(1);
      #pragma unroll
      for (int ks = 0; ks < 4; ++ks)
        sacc = __builtin_amdgcn_mfma_f32_32x32x16_bf16(kf[ks], qa[g][ks], sacc, 0, 0, 0);
      __builtin_amdgcn_s_setprio(0);

      float pv[16]; float ps = 0.f;
      #pragma unroll
      for (int r = 0; r < 16; ++r) { pv[r] = EXP2(sacc[r]); ps += pv[r]; }
      ps += __shfl_xor(ps, 32, 64);
      if (g == 0) l_run0 += ps; else l_run1 += ps;

      unsigned pk[8];
      #pragma unroll
      for (int i = 0; i < 8; ++i) pk[i] = pack2(pv[2 * i], pv[2 * i + 1]);

      unsigned w[8];
      #pragma unroll
      for (int g2 = 0; g2 < 2; ++g2) {
        const int bx = g2 * 4;
        #pragma unroll
        for (int ii = 0; ii < 2; ++ii) {
          const unsigned lo = pk[bx + ii], hi2 = pk[bx + 2 + ii];
          const unsigned s  = hi ? lo : hi2;
          const unsigned xs = __shfl_xor(s, 32, 64);
          w[bx + ii]     = hi ? xs  : lo;
          w[bx + 2 + ii] = hi ? hi2 : xs;
        }
      }
      const u32x4 pw0 = {w[0], w[1], w[2], w[3]};
      const u32x4 pw1 = {w[4], w[5], w[6], w[7]};
      const bf16x8 pb0 = __builtin_bit_cast(bf16x8, pw0);
      const bf16x8 pb1 = __builtin_bit_cast(bf16x8, pw1);

      __builtin_amdgcn_s_setprio(1);
      if (g == 0) {
        #pragma unroll
        for (int dt = 0; dt < 2; ++dt) {
          oaccA[dt] = __builtin_amdgcn_mfma_f32_32x32x16_bf16(vf[dt][0], pb0, oaccA[dt], 0, 0, 0);
          oaccA[dt] = __builtin_amdgcn_mfma_f32_32x32x16_bf16(vf[dt][1], pb1, oaccA[dt], 0, 0, 0);
        }
      } else {
        #pragma unroll
        for (int dt = 0; dt < 2; ++dt) {
          oaccB[dt] = __builtin_amdgcn_mfma_f32_32x32x16_bf16(vf[dt][0], pb0, oaccB[dt], 0, 0, 0);
          oaccB[dt] = __builtin_amdgcn_mfma_f32_32x32x16_bf16(vf[dt][1], pb1, oaccB[dt], 0, 0, 0);
        }
      }
      __builtin_amdgcn_s_setprio(0);
    }
  }
#undef STAGE_K

  if (hi == 0) { Lsh[wave][0][li] = l_run0; Lsh[wave][1][li] = l_run1; }
  __syncthreads();

  #pragma unroll
  for (int ss = 0; ss < 4; ++ss) {
    if (wave == ss) {
      #pragma unroll
      for (int g = 0; g < 2; ++g)
        #pragma unroll
        for (int dt = 0; dt < 2; ++dt)
          #pragma unroll
          for (int r = 0; r < 16; ++r) {
            const int d = dt * 32 + (r & 3) + 8 * (r >> 2) + 4 * hi;
            const float val = (g == 0) ? oaccA[dt][r] : oaccB[dt][r];
            if (ss == 0) Osh[d][g * 32 + li] = val;
            else         Osh[d][g * 32 + li] += val;
          }
    }
    __syncthreads();
  }

  // final: normalize + coalesced store (64 q rows)
  #pragma unroll
  for (int rr = 0; rr < 2; ++rr) {
    const int qq = tid >> 3, c8 = (tid & 7) * 8;
    const float lg = Lsh[0][rr][qq] + Lsh[1][rr][qq] + Lsh[2][rr][qq] + Lsh[3][rr][qq];
    const float rl = 1.f / lg;
    u32x4 ow;
    #pragma unroll
    for (int j = 0; j < 4; ++j)
      ow[j] = pack2(Osh[c8 + 2 * j][rr * 32 + qq] * rl, Osh[c8 + 2 * j + 1][rr * 32 + qq] * rl);
    *(u32x4*)(o + (size_t)(b * LQ_ + qt * 64 + rr * 32 + qq) * 1024 + h * 64 + c8) = ow;
  }
}

extern "C" void kernel_launch(void* const* d_in, const int* in_sizes, int n_in,
                              void* d_out, int out_size, void* d_ws, size_t ws_size,
                              hipStream_t stream) {
  const float* query   = (const float*)d_in[0];
  const float* context = (const float*)d_in[1];
  const float* Wq      = (const float*)d_in[2];
  const float* bq      = (const float*)d_in[3];
  const float* Wkv     = (const float*)d_in[4];
  const float* bkv     = (const float*)d_in[5];
  const float* Wout    = (const float*)d_in[6];
  const float* bout    = (const float*)d_in[7];

  char* p = (char*)d_ws;
  bf16_t* queryb = (bf16_t*)p; p += (size_t)4096 * 1024 * 2;
  bf16_t* ctxb   = (bf16_t*)p; p += (size_t)4096 * 1024 * 2;
  bf16_t* Wq_t   = (bf16_t*)p; p += (size_t)1024 * 1024 * 2;
  bf16_t* Wkv_t  = (bf16_t*)p; p += (size_t)2048 * 1024 * 2;
  bf16_t* Wout_t = (bf16_t*)p; p += (size_t)1024 * 1024 * 2;
  bf16_t* q_s    = (bf16_t*)p; p += (size_t)4096 * 1024 * 2;
  bf16_t* k_s    = (bf16_t*)p; p += (size_t)4096 * 1024 * 2;
  bf16_t* v_t    = (bf16_t*)p; p += (size_t)4096 * 1024 * 2;
  bf16_t* attnb  = (bf16_t*)p; p += (size_t)4096 * 1024 * 2;
  if ((size_t)(p - (char*)d_ws) > ws_size) return;

  prep_kernel<<<12288, 256, 0, stream>>>(query, context, queryb, ctxb,
                                         Wq, Wkv, Wout, Wq_t, Wkv_t, Wout_t);
  proj_fused_kernel<<<dim3(48, 32), 256, 0, stream>>>(queryb, ctxb, Wq_t, Wkv_t,
                                                      bq, bkv, q_s, k_s, v_t);
  attn_kernel<<<dim3(1024), 256, 0, stream>>>(q_s, k_s, v_t, attnb);
  gemm_out_kernel<<<dim3(16, 32), 256, 0, stream>>>(attnb, Wout_t, bout, (float*)d_out);
}

// Round 23
// 138.976 us; speedup vs baseline: 2.5032x; 1.0389x over previous
//
#include <hip/hip_runtime.h>
#include <hip/hip_bf16.h>
#include <stdint.h>

typedef __bf16 bf16_t;
typedef __bf16 bf16x8 __attribute__((ext_vector_type(8)));
typedef __bf16 bf16x4_t __attribute__((ext_vector_type(4)));
typedef float f32x4 __attribute__((ext_vector_type(4)));
typedef float f32x16 __attribute__((ext_vector_type(16)));
typedef unsigned int u32x4 __attribute__((ext_vector_type(4)));

#define B_   2
#define H_   16
#define D_   64
#define LQ_  2048
#define LC_  2048
#define M_   1024

#define EXP2(x) __builtin_amdgcn_exp2f(x)

// VGPR-pin rule (rounds 16/19/21): __launch_bounds__(256,n) caps the allocator
// at ~256/n VGPRs on gfx950. Never pin above 256/measured-VGPR.

__device__ __forceinline__ void gload_lds16(const void* g, void* l) {
  __builtin_amdgcn_global_load_lds((__attribute__((address_space(1))) unsigned int*)(g),
                                   (__attribute__((address_space(3))) unsigned int*)(l),
                                   16, 0, 0);
}

__device__ __forceinline__ unsigned pack2(float a, float b) {
  __bf16 x = (__bf16)a, y = (__bf16)b;
  unsigned short ux = __builtin_bit_cast(unsigned short, x);
  unsigned short uy = __builtin_bit_cast(unsigned short, y);
  return (unsigned)ux | ((unsigned)uy << 16);
}

// ---------------- merged prep: input cvt + 3 weight transposes, one dispatch ----------------
__global__ void prep_kernel(const float* __restrict__ query, const float* __restrict__ context,
                            bf16_t* __restrict__ queryb, bf16_t* __restrict__ ctxb,
                            const float* __restrict__ Wq, const float* __restrict__ Wkv,
                            const float* __restrict__ Wout,
                            bf16_t* __restrict__ Wq_t, bf16_t* __restrict__ Wkv_t,
                            bf16_t* __restrict__ Wout_t) {
  __shared__ float tile[32][33];
  const int bid = blockIdx.x;
  if (bid < 8192) {
    const int n4each = 4096 * 1024 / 4;
    int i = bid * 256 + threadIdx.x;
    const float* in = (i < n4each) ? query : context;
    bf16_t* out = (i < n4each) ? queryb : ctxb;
    const int j = (i < n4each) ? i : (i - n4each);
    const float4 f = ((const float4*)in)[j];
    bf16x4_t o4;
    o4[0] = (__bf16)f.x; o4[1] = (__bf16)f.y; o4[2] = (__bf16)f.z; o4[3] = (__bf16)f.w;
    ((bf16x4_t*)out)[j] = o4;
    return;
  }
  int tb = bid - 8192;
  const float* in; bf16_t* out; int N, kvperm;
  if (tb < 1024)      { in = Wq;   out = Wq_t;   N = 1024; kvperm = 0; }
  else if (tb < 3072) { tb -= 1024; in = Wkv;  out = Wkv_t;  N = 2048; kvperm = 1; }
  else                { tb -= 3072; in = Wout; out = Wout_t; N = 1024; kvperm = 0; }
  const int K = 1024;
  const int nb = N / 32;
  const int n0 = (tb % nb) * 32, k0 = (tb / nb) * 32;
  const int tx = threadIdx.x & 31, ty = threadIdx.x >> 5;
  #pragma unroll
  for (int r = ty; r < 32; r += 8)
    tile[r][tx] = in[(size_t)(k0 + r) * N + (n0 + tx)];
  __syncthreads();
  #pragma unroll
  for (int r = ty; r < 32; r += 8) {
    const int n = n0 + r;
    const int orow = kvperm ? ((n & ~127) | ((n & 1) << 6) | ((n >> 1) & 63)) : n;
    out[(size_t)orow * K + (k0 + tx)] = (__bf16)tile[tx][r];
  }
}

// ---------------- fused Q-proj + KV-proj GEMM v3 (FROZEN): counted-vmcnt dbuf ----------------
__global__ __launch_bounds__(256, 3)
void proj_fused_kernel(const bf16_t* __restrict__ Aq, const bf16_t* __restrict__ Akv,
                       const bf16_t* __restrict__ Wq_t, const bf16_t* __restrict__ Wkv_t,
                       const float* __restrict__ bq, const float* __restrict__ bkv,
                       bf16_t* __restrict__ q_s, bf16_t* __restrict__ k_s,
                       bf16_t* __restrict__ v_t) {
  __shared__ __attribute__((aligned(16))) bf16_t ldsA[2][128 * 64];
  __shared__ __attribute__((aligned(16))) bf16_t ldsB[2][64 * 64];
  const int tid  = threadIdx.x;
  const int wave = tid >> 6, lane = tid & 63;
  const int bid  = blockIdx.x + 48 * blockIdx.y;
  const int nbid = (bid & 7) * 192 + (bid >> 3);
  const int ny = nbid / 48, nx = nbid % 48;
  const bool isq = (nx < 16);
  const bf16_t* A  = isq ? Aq : Akv;
  const bf16_t* Bt = isq ? Wq_t : Wkv_t;
  const int n0 = (isq ? nx : (nx - 16)) * 64;
  const int m0 = ny * 128;
  const int K  = 1024;
  const int wr = wave >> 1, wc = wave & 1;
  const int lrow = lane & 15, lg = lane >> 4;
  const int srow = lane >> 3;
  const int sc8  = ((lane & 7) ^ srow) * 8;

#define PSTAGE(T, BUF) do {                                                      \
    const int kk_ = (T) * 64;                                                    \
    _Pragma("unroll")                                                            \
    for (int i_ = 0; i_ < 4; ++i_) {                                             \
      const int c_ = wave * 4 + i_;                                              \
      gload_lds16(A + (size_t)(m0 + c_ * 8 + srow) * K + (kk_ + sc8),            \
                  ldsA[BUF] + c_ * 512);                                         \
    }                                                                            \
    _Pragma("unroll")                                                            \
    for (int i_ = 0; i_ < 2; ++i_) {                                             \
      const int c_ = wave * 2 + i_;                                              \
      gload_lds16(Bt + (size_t)(n0 + c_ * 8 + srow) * K + (kk_ + sc8),           \
                  ldsB[BUF] + c_ * 512);                                         \
    }                                                                            \
  } while (0)

  f32x4 acc[4][2] = {};

  PSTAGE(0, 0);
  asm volatile("s_waitcnt vmcnt(0)" ::: "memory");
  __builtin_amdgcn_s_barrier();
  PSTAGE(1, 1);

  #pragma unroll 1
  for (int kt = 0; kt < 16; ++kt) {
    const int buf = kt & 1;
    bf16x8 af[2][4], bfv[2][2];
    #pragma unroll
    for (int ks = 0; ks < 2; ++ks) {
      #pragma unroll
      for (int mi = 0; mi < 4; ++mi)
        af[ks][mi] = *(const bf16x8*)(ldsA[buf] + (wr * 64 + mi * 16 + lrow) * 64 +
                                      (((ks * 4 + lg) ^ (lrow & 7)) * 8));
      #pragma unroll
      for (int ni = 0; ni < 2; ++ni)
        bfv[ks][ni] = *(const bf16x8*)(ldsB[buf] + (wc * 32 + ni * 16 + lrow) * 64 +
                                       (((ks * 4 + lg) ^ (lrow & 7)) * 8));
    }
    asm volatile("s_waitcnt lgkmcnt(0)" ::: "memory");
    __builtin_amdgcn_sched_barrier(0);
    __builtin_amdgcn_s_barrier();

    int t2 = kt + 2; if (t2 > 15) t2 = 15;
    PSTAGE(t2, buf);

    #pragma unroll
    for (int ks = 0; ks < 2; ++ks)
      #pragma unroll
      for (int mi = 0; mi < 4; ++mi)
        #pragma unroll
        for (int ni = 0; ni < 2; ++ni)
          acc[mi][ni] = __builtin_amdgcn_mfma_f32_16x16x32_bf16(af[ks][mi], bfv[ks][ni],
                                                                acc[mi][ni], 0, 0, 0);

    asm volatile("s_waitcnt vmcnt(6)" ::: "memory");
    __builtin_amdgcn_sched_barrier(0);
    __builtin_amdgcn_s_barrier();
  }
#undef PSTAGE

  #pragma unroll
  for (int mi = 0; mi < 4; ++mi) {
    const int rbase = m0 + wr * 64 + mi * 16 + lg * 4;
    #pragma unroll
    for (int ni = 0; ni < 2; ++ni) {
      const int col = n0 + wc * 32 + ni * 16 + lrow;
      if (isq) {
        const float bv = bq[col];
        #pragma unroll
        for (int j = 0; j < 4; ++j)
          q_s[(size_t)(rbase + j) * 1024 + col] =
              (__bf16)((acc[mi][ni][j] + bv) * 0.18033688011112042f);
      } else {
        const int hh = col >> 7, cbit = (col >> 6) & 1, d = col & 63;
        const float bv = bkv[hh * 128 + d * 2 + cbit];
        #pragma unroll
        for (int j = 0; j < 4; ++j) {
          const int row = rbase + j;
          const int bi = row >> 11, lc = row & 2047;
          const float val = acc[mi][ni][j] + bv;
          if (cbit == 0)
            k_s[((size_t)(bi * 16 + hh) * 2048 + lc) * 64 + d] = (__bf16)val;
          else
            v_t[(((size_t)(bi * 16 + hh) * 64 + (lc >> 5)) * 64 + d) * 32 + (lc & 31)] = (__bf16)val;
        }
      }
    }
  }
}

// ---------------- out-proj GEMM v3 (FROZEN): counted-vmcnt dbuf ----------------
__global__ __launch_bounds__(256, 3)
void gemm_out_kernel(const bf16_t* __restrict__ A, const bf16_t* __restrict__ Bt,
                     const float* __restrict__ bias, float* __restrict__ out0) {
  __shared__ __attribute__((aligned(16))) bf16_t ldsA[2][128 * 64];
  __shared__ __attribute__((aligned(16))) bf16_t ldsB[2][64 * 64];
  const int tid  = threadIdx.x;
  const int wave = tid >> 6, lane = tid & 63;
  const int bid  = blockIdx.x + 16 * blockIdx.y;
  const int nbid = (bid & 7) * 64 + (bid >> 3);
  const int m0 = (nbid >> 4) * 128, n0 = (nbid & 15) * 64;
  const int K = 1024, N = 1024;
  const int wr = wave >> 1, wc = wave & 1;
  const int lrow = lane & 15, lg = lane >> 4;
  const int srow = lane >> 3;
  const int sc8  = ((lane & 7) ^ srow) * 8;

#define OSTAGE(T, BUF) do {                                                      \
    const int kk_ = (T) * 64;                                                    \
    _Pragma("unroll")                                                            \
    for (int i_ = 0; i_ < 4; ++i_) {                                             \
      const int c_ = wave * 4 + i_;                                              \
      gload_lds16(A + (size_t)(m0 + c_ * 8 + srow) * K + (kk_ + sc8),            \
                  ldsA[BUF] + c_ * 512);                                         \
    }                                                                            \
    _Pragma("unroll")                                                            \
    for (int i_ = 0; i_ < 2; ++i_) {                                             \
      const int c_ = wave * 2 + i_;                                              \
      gload_lds16(Bt + (size_t)(n0 + c_ * 8 + srow) * K + (kk_ + sc8),           \
                  ldsB[BUF] + c_ * 512);                                         \
    }                                                                            \
  } while (0)

  f32x4 acc[4][2] = {};

  OSTAGE(0, 0);
  asm volatile("s_waitcnt vmcnt(0)" ::: "memory");
  __builtin_amdgcn_s_barrier();
  OSTAGE(1, 1);

  #pragma unroll 1
  for (int kt = 0; kt < 16; ++kt) {
    const int buf = kt & 1;
    bf16x8 af[2][4], bfv[2][2];
    #pragma unroll
    for (int ks = 0; ks < 2; ++ks) {
      #pragma unroll
      for (int mi = 0; mi < 4; ++mi)
        af[ks][mi] = *(const bf16x8*)(ldsA[buf] + (wr * 64 + mi * 16 + lrow) * 64 +
                                      (((ks * 4 + lg) ^ (lrow & 7)) * 8));
      #pragma unroll
      for (int ni = 0; ni < 2; ++ni)
        bfv[ks][ni] = *(const bf16x8*)(ldsB[buf] + (wc * 32 + ni * 16 + lrow) * 64 +
                                       (((ks * 4 + lg) ^ (lrow & 7)) * 8));
    }
    asm volatile("s_waitcnt lgkmcnt(0)" ::: "memory");
    __builtin_amdgcn_sched_barrier(0);
    __builtin_amdgcn_s_barrier();

    int t2 = kt + 2; if (t2 > 15) t2 = 15;
    OSTAGE(t2, buf);

    #pragma unroll
    for (int ks = 0; ks < 2; ++ks)
      #pragma unroll
      for (int mi = 0; mi < 4; ++mi)
        #pragma unroll
        for (int ni = 0; ni < 2; ++ni)
          acc[mi][ni] = __builtin_amdgcn_mfma_f32_16x16x32_bf16(af[ks][mi], bfv[ks][ni],
                                                                acc[mi][ni], 0, 0, 0);

    asm volatile("s_waitcnt vmcnt(6)" ::: "memory");
    __builtin_amdgcn_sched_barrier(0);
    __builtin_amdgcn_s_barrier();
  }
#undef OSTAGE

  #pragma unroll
  for (int mi = 0; mi < 4; ++mi) {
    const int rbase = m0 + wr * 64 + mi * 16 + lg * 4;
    #pragma unroll
    for (int ni = 0; ni < 2; ++ni) {
      const int col = n0 + wc * 32 + ni * 16 + lrow;
      const float bv = bias[col];
      #pragma unroll
      for (int j = 0; j < 4; ++j)
        out0[(size_t)(rbase + j) * N + col] = acc[mi][ni][j] + bv;
    }
  }
}

// ---------------- flash attention v20: K-row staging permutation kills P-exchange ----------------
// The S^T->PV cross-half exchange existed because crow(r,hi) interleaves kv
// across lane halves. Staging K with L(p) = (((p>>2)^(p>>3))&1) ? p^12 : p
// (swaps row blocks [4..7]<->[8..11], [20..23]<->[24..27]) makes sacc register
// order = PV B-frag order directly (verified lo/hi x both MFMAs). Deletes 8
// shuffles + 8 selects per iter and shortens the exp->PV chain. V & QK paths
// untouched; col swizzle keyed on PHYSICAL row bits cancels as before.
// l cross-half shuffle deferred to epilogue (2 total instead of 32; changes
// only summation grouping -> canary shifts benignly).
__global__ __launch_bounds__(256, 2)
void attn_kernel(const bf16_t* __restrict__ q, const bf16_t* __restrict__ k,
                 const bf16_t* __restrict__ vt, bf16_t* __restrict__ o) {
  __shared__ __attribute__((aligned(16))) bf16_t stage[4][2048];
  __shared__ float Osh[64][64];          // [d][q] f32 (64 q rows)
  __shared__ float Lsh[4][2][32];

  const int tid  = threadIdx.x;
  const int wave = tid >> 6, lane = tid & 63;
  const int li = lane & 31, hi = lane >> 5;

  // XCD-clustered decode: 8 XCDs x (4 heads x 32 q-tiles-of-64), bijective
  const int bid  = blockIdx.x;
  const int xcd  = bid & 7, slot = bid >> 3;
  const int bh   = xcd * 4 + (slot >> 5);
  const int qt   = slot & 31;
  const int b    = bh >> 4, h = bh & 15;

  bf16x8 qa[2][4];
  #pragma unroll
  for (int g = 0; g < 2; ++g) {
    const bf16_t* qp = q + (size_t)(b * LQ_ + qt * 64 + g * 32 + li) * 1024 + h * 64 + hi * 8;
    #pragma unroll
    for (int ks = 0; ks < 4; ++ks) qa[g][ks] = *(const bf16x8*)(qp + ks * 16);
  }
  asm volatile("s_waitcnt vmcnt(0)" ::: "memory");

  const int kv0 = wave * (LC_ / 4);
  const bf16_t* kbase  = k  + (size_t)bh * LC_ * 64 + (size_t)kv0 * 64;
  const bf16_t* vtbase = vt + ((size_t)bh * 64 + wave * 16) * 2048;

  // per-lane K source offsets with row permutation L(p) (p = physical row)
  const int srow8 = lane >> 3;
  const int scol  = ((lane & 7) ^ srow8) * 8;   // swizzle keyed on p&7 == srow8
  size_t koffp[4];
  #pragma unroll
  for (int i = 0; i < 4; ++i) {
    const int p  = i * 8 + srow8;
    const int Lp = (((p >> 2) ^ (p >> 3)) & 1) ? (p ^ 12) : p;
    koffp[i] = (size_t)Lp * 64 + scol;
  }

  bf16_t* lk = &stage[wave][0];

#define STAGE_K(T) do {                                                          \
    const bf16_t* kc_ = kbase + (size_t)(T) * 2048;                              \
    _Pragma("unroll")                                                            \
    for (int i_ = 0; i_ < 4; ++i_)                                               \
      gload_lds16(kc_ + koffp[i_], lk + i_ * 512);                               \
  } while (0)

  f32x16 oaccA[2] = {};
  f32x16 oaccB[2] = {};
  float l_run0 = 0.f, l_run1 = 0.f;

  STAGE_K(0);

  #pragma unroll 1
  for (int t = 0; t < 16; ++t) {
    asm volatile("s_waitcnt vmcnt(0)" ::: "memory");
    __builtin_amdgcn_sched_barrier(0);

    bf16x8 vf[2][2];
    {
      const bf16_t* vtile = vtbase + (size_t)t * 2048;
      #pragma unroll
      for (int dt = 0; dt < 2; ++dt)
        #pragma unroll
        for (int ks2 = 0; ks2 < 2; ++ks2)
          vf[dt][ks2] = *(const bf16x8*)(vtile + (dt * 32 + li) * 32 + ks2 * 16 + hi * 8);
    }
    __builtin_amdgcn_sched_barrier(0);

    bf16x8 kf[4];
    #pragma unroll
    for (int ks = 0; ks < 4; ++ks)
      kf[ks] = *(const bf16x8*)(lk + li * 64 + (((hi + ks * 2) ^ (li & 7)) * 8));

    asm volatile("s_waitcnt lgkmcnt(0)" ::: "memory");
    __builtin_amdgcn_sched_barrier(0);

    int t2 = t + 1; if (t2 > 15) t2 = 15;
    STAGE_K(t2);

    #pragma unroll
    for (int g = 0; g < 2; ++g) {
      f32x16 sacc = {};
      __builtin_amdgcn_s_setprio(1);
      #pragma unroll
      for (int ks = 0; ks < 4; ++ks)
        sacc = __builtin_amdgcn_mfma_f32_32x32x16_bf16(kf[ks], qa[g][ks], sacc, 0, 0, 0);
      __builtin_amdgcn_s_setprio(0);

      float pv[16]; float ps = 0.f;
      #pragma unroll
      for (int r = 0; r < 16; ++r) { pv[r] = EXP2(sacc[r]); ps += pv[r]; }
      if (g == 0) l_run0 += ps; else l_run1 += ps;   // cross-half deferred

      // direct B-frag pack: register order == PV layout (staging permutation)
      const u32x4 pw0 = {pack2(pv[0], pv[1]),  pack2(pv[2], pv[3]),
                         pack2(pv[4], pv[5]),  pack2(pv[6], pv[7])};
      const u32x4 pw1 = {pack2(pv[8], pv[9]),  pack2(pv[10], pv[11]),
                         pack2(pv[12], pv[13]), pack2(pv[14], pv[15])};
      const bf16x8 pb0 = __builtin_bit_cast(bf16x8, pw0);
      const bf16x8 pb1 = __builtin_bit_cast(bf16x8, pw1);

      __builtin_amdgcn_s_setprio(1);
      if (g == 0) {
        #pragma unroll
        for (int dt = 0; dt < 2; ++dt) {
          oaccA[dt] = __builtin_amdgcn_mfma_f32_32x32x16_bf16(vf[dt][0], pb0, oaccA[dt], 0, 0, 0);
          oaccA[dt] = __builtin_amdgcn_mfma_f32_32x32x16_bf16(vf[dt][1], pb1, oaccA[dt], 0, 0, 0);
        }
      } else {
        #pragma unroll
        for (int dt = 0; dt < 2; ++dt) {
          oaccB[dt] = __builtin_amdgcn_mfma_f32_32x32x16_bf16(vf[dt][0], pb0, oaccB[dt], 0, 0, 0);
          oaccB[dt] = __builtin_amdgcn_mfma_f32_32x32x16_bf16(vf[dt][1], pb1, oaccB[dt], 0, 0, 0);
        }
      }
      __builtin_amdgcn_s_setprio(0);
    }
  }
#undef STAGE_K

  // deferred cross-half l reduction (2 shuffles total for the whole kernel)
  l_run0 += __shfl_xor(l_run0, 32, 64);
  l_run1 += __shfl_xor(l_run1, 32, 64);

  if (hi == 0) { Lsh[wave][0][li] = l_run0; Lsh[wave][1][li] = l_run1; }
  __syncthreads();

  #pragma unroll
  for (int ss = 0; ss < 4; ++ss) {
    if (wave == ss) {
      #pragma unroll
      for (int g = 0; g < 2; ++g)
        #pragma unroll
        for (int dt = 0; dt < 2; ++dt)
          #pragma unroll
          for (int r = 0; r < 16; ++r) {
            const int d = dt * 32 + (r & 3) + 8 * (r >> 2) + 4 * hi;
            const float val = (g == 0) ? oaccA[dt][r] : oaccB[dt][r];
            if (ss == 0) Osh[d][g * 32 + li] = val;
            else         Osh[d][g * 32 + li] += val;
          }
    }
    __syncthreads();
  }

  // final: normalize + coalesced store (64 q rows)
  #pragma unroll
  for (int rr = 0; rr < 2; ++rr) {
    const int qq = tid >> 3, c8 = (tid & 7) * 8;
    const float lg = Lsh[0][rr][qq] + Lsh[1][rr][qq] + Lsh[2][rr][qq] + Lsh[3][rr][qq];
    const float rl = 1.f / lg;
    u32x4 ow;
    #pragma unroll
    for (int j = 0; j < 4; ++j)
      ow[j] = pack2(Osh[c8 + 2 * j][rr * 32 + qq] * rl, Osh[c8 + 2 * j + 1][rr * 32 + qq] * rl);
    *(u32x4*)(o + (size_t)(b * LQ_ + qt * 64 + rr * 32 + qq) * 1024 + h * 64 + c8) = ow;
  }
}

extern "C" void kernel_launch(void* const* d_in, const int* in_sizes, int n_in,
                              void* d_out, int out_size, void* d_ws, size_t ws_size,
                              hipStream_t stream) {
  const float* query   = (const float*)d_in[0];
  const float* context = (const float*)d_in[1];
  const float* Wq      = (const float*)d_in[2];
  const float* bq      = (const float*)d_in[3];
  const float* Wkv     = (const float*)d_in[4];
  const float* bkv     = (const float*)d_in[5];
  const float* Wout    = (const float*)d_in[6];
  const float* bout    = (const float*)d_in[7];

  char* p = (char*)d_ws;
  bf16_t* queryb = (bf16_t*)p; p += (size_t)4096 * 1024 * 2;
  bf16_t* ctxb   = (bf16_t*)p; p += (size_t)4096 * 1024 * 2;
  bf16_t* Wq_t   = (bf16_t*)p; p += (size_t)1024 * 1024 * 2;
  bf16_t* Wkv_t  = (bf16_t*)p; p += (size_t)2048 * 1024 * 2;
  bf16_t* Wout_t = (bf16_t*)p; p += (size_t)1024 * 1024 * 2;
  bf16_t* q_s    = (bf16_t*)p; p += (size_t)4096 * 1024 * 2;
  bf16_t* k_s    = (bf16_t*)p; p += (size_t)4096 * 1024 * 2;
  bf16_t* v_t    = (bf16_t*)p; p += (size_t)4096 * 1024 * 2;
  bf16_t* attnb  = (bf16_t*)p; p += (size_t)4096 * 1024 * 2;
  if ((size_t)(p - (char*)d_ws) > ws_size) return;

  prep_kernel<<<12288, 256, 0, stream>>>(query, context, queryb, ctxb,
                                         Wq, Wkv, Wout, Wq_t, Wkv_t, Wout_t);
  proj_fused_kernel<<<dim3(48, 32), 256, 0, stream>>>(queryb, ctxb, Wq_t, Wkv_t,
                                                      bq, bkv, q_s, k_s, v_t);
  attn_kernel<<<dim3(1024), 256, 0, stream>>>(q_s, k_s, v_t, attnb);
  gemm_out_kernel<<<dim3(16, 32), 256, 0, stream>>>(attnb, Wout_t, bout, (float*)d_out);
}